// Round 3
// baseline (24810.091 us; speedup 1.0000x reference)
//
#include <hip/hip_runtime.h>
#include <math.h>

// Problem constants (fixed by the harness).
#define BB 4096
#define TT 2048
#define LL 100

constexpr int NB = 16;        // batch chains per workgroup
constexpr int WG = 512;       // threads per workgroup (8 waves)
constexpr int H1STRIDE = 116; // padded LDS row stride (floats): 116*4=464B, 16B-aligned, banks spread
constexpr int XTILE = 64;     // input timesteps staged per LDS tile

__device__ __forceinline__ float fsig(float x) {
    // 1/(1+e^-x); __expf -> v_exp_f32 path, ~2ulp. Saturates cleanly at +-inf.
    return 1.0f / (1.0f + __expf(-x));
}
__device__ __forceinline__ float ftanh(float x) {
    // tanh via exp(2|x|): overflow-safe (e=inf -> r=1), then restore sign.
    float a = fabsf(x);
    float e = __expf(2.0f * a);
    float r = 1.0f - 2.0f / (e + 1.0f);
    return copysignf(r, x);
}

// Quad butterfly reduce via DPP (VALU pipe, ~4cyc) instead of __shfl_xor
// (ds_bpermute: LDS pipe, ~100cyc latency, was ~800 extra LDS ops/CU/step).
// quad_perm[1,0,3,2] = 0xB1 (xor 1), quad_perm[2,3,0,1] = 0x4E (xor 2).
#define DPP_QUAD_REDUCE(x)                                                        \
    x += __int_as_float(__builtin_amdgcn_mov_dpp(__float_as_int(x), 0xB1, 0xF, 0xF, true)); \
    x += __int_as_float(__builtin_amdgcn_mov_dpp(__float_as_int(x), 0x4E, 0xF, 0xF, true));

__global__ void __launch_bounds__(WG)
__attribute__((amdgpu_waves_per_eu(2, 2)))
lstm2_kernel(const float* __restrict__ input,   // [B,T]
             const float* __restrict__ W_ih1,   // [400,1]
             const float* __restrict__ W_hh1,   // [400,100]
             const float* __restrict__ b_ih1,   // [400]
             const float* __restrict__ b_hh1,   // [400]
             const float* __restrict__ W_ih2,   // [4,100]
             const float* __restrict__ W_hh2,   // [4,1]
             const float* __restrict__ b_ih2,   // [4]
             const float* __restrict__ b_hh2,   // [4]
             float* __restrict__ out)           // [B,T]
{
    __shared__ __align__(16) float h1buf[2][NB][H1STRIDE]; // double-buffered h1 state
    __shared__ float xs[NB][XTILE];                        // staged input tile

    const int tid = threadIdx.x;
    const int bg0 = blockIdx.x * NB;

    // Zero h1 buffers (including col padding 100..115 -> must stay 0 forever).
    for (int i = tid; i < 2 * NB * H1STRIDE; i += WG)
        (&h1buf[0][0][0])[i] = 0.0f;

    const bool isL1 = (tid < 4 * LL);   // threads 0..399
    const bool isL2 = (tid >= 448);     // wave 7: 64 lanes = 16 items x 4 gates

    // ---- per-thread persistent state ----
    // wreg is shared storage: layer-1 threads use [0..111] as W_hh1 slices,
    // layer-2 threads use [0..99] as a W_ih2 row.
    float wreg[112];
    float wx[4], bias[4];
    float c1[NB];

    const int s = tid & 3;    // col slice (28 cols each, zero-padded)
    const int k = tid >> 2;   // hidden unit 0..99

    if (isL1) {
#pragma unroll
        for (int g = 0; g < 4; ++g) {
            const int row = g * LL + k;
#pragma unroll
            for (int j = 0; j < 28; ++j) {
                const int c = 28 * s + j;
                wreg[g * 28 + j] = (c < LL) ? W_hh1[row * LL + c] : 0.0f;
            }
            wx[g] = W_ih1[row];
            bias[g] = b_ih1[row] + b_hh1[row];
        }
#pragma unroll
        for (int b = 0; b < NB; ++b) c1[b] = 0.0f;
    }

    const int m = tid - 448;       // lane within wave 7
    const int b2i = (m >> 2) & 15; // item
    const int gg = m & 3;          // gate (i,f,g,o)
    float wh2 = 0.0f, bias2 = 0.0f, h2 = 0.0f, c2 = 0.0f;
    if (isL2) {
#pragma unroll
        for (int j = 0; j < LL; ++j) wreg[j] = W_ih2[gg * LL + j];
        wh2 = W_hh2[gg];
        bias2 = b_ih2[gg] + b_hh2[gg];
    }

    __syncthreads();

    // t = 0..T-1: layer-1 computes h1_t ; wave 7 (t>=1) computes h2_{t-1} (one step behind).
    // t = T: layer-2 tail only.
    for (int t = 0; t <= TT; ++t) {
        if ((t & (XTILE - 1)) == 0 && t < TT) {
            // stage next 64 timesteps of input for our 16 items (coalesced)
            for (int u = tid; u < NB * XTILE; u += WG) {
                const int b = u >> 6, ti = u & (XTILE - 1);
                xs[b][ti] = input[(size_t)(bg0 + b) * TT + t + ti];
            }
            __syncthreads();
        }
        const int cur = t & 1, prev = cur ^ 1;

        if (t < TT && isL1) {
            const float* hb = &h1buf[prev][0][0];
#pragma unroll 1
            for (int b = 0; b < NB; ++b) {
                const float* hrow = hb + b * H1STRIDE + 28 * s;
                float a0 = 0.f, a1 = 0.f, a2 = 0.f, a3 = 0.f;
#pragma unroll
                for (int jb = 0; jb < 7; ++jb) {
                    const float4 h4 = *(const float4*)(hrow + 4 * jb);
                    a0 = fmaf(wreg[0 * 28 + 4 * jb + 0], h4.x, a0);
                    a1 = fmaf(wreg[1 * 28 + 4 * jb + 0], h4.x, a1);
                    a2 = fmaf(wreg[2 * 28 + 4 * jb + 0], h4.x, a2);
                    a3 = fmaf(wreg[3 * 28 + 4 * jb + 0], h4.x, a3);
                    a0 = fmaf(wreg[0 * 28 + 4 * jb + 1], h4.y, a0);
                    a1 = fmaf(wreg[1 * 28 + 4 * jb + 1], h4.y, a1);
                    a2 = fmaf(wreg[2 * 28 + 4 * jb + 1], h4.y, a2);
                    a3 = fmaf(wreg[3 * 28 + 4 * jb + 1], h4.y, a3);
                    a0 = fmaf(wreg[0 * 28 + 4 * jb + 2], h4.z, a0);
                    a1 = fmaf(wreg[1 * 28 + 4 * jb + 2], h4.z, a1);
                    a2 = fmaf(wreg[2 * 28 + 4 * jb + 2], h4.z, a2);
                    a3 = fmaf(wreg[3 * 28 + 4 * jb + 2], h4.z, a3);
                    a0 = fmaf(wreg[0 * 28 + 4 * jb + 3], h4.w, a0);
                    a1 = fmaf(wreg[1 * 28 + 4 * jb + 3], h4.w, a1);
                    a2 = fmaf(wreg[2 * 28 + 4 * jb + 3], h4.w, a2);
                    a3 = fmaf(wreg[3 * 28 + 4 * jb + 3], h4.w, a3);
                }
                // reduce across the 4 col-slices (lane bits 0..1) via DPP quad butterflies
                DPP_QUAD_REDUCE(a0)
                DPP_QUAD_REDUCE(a1)
                DPP_QUAD_REDUCE(a2)
                DPP_QUAD_REDUCE(a3)

                const float xt = xs[b][t & (XTILE - 1)];
                const float pi = a0 + wx[0] * xt + bias[0];
                const float pf = a1 + wx[1] * xt + bias[1];
                const float pg = a2 + wx[2] * xt + bias[2];
                const float po = a3 + wx[3] * xt + bias[3];

                const float ig = fsig(pi);
                const float fg = fsig(pf);
                const float gv = ftanh(pg);
                const float og = fsig(po);

                const float c = fg * c1[b] + ig * gv;
                c1[b] = c;
                const float h = og * ftanh(c);
                if (s == 0) h1buf[cur][b][k] = h;
            }
        }

        if (t >= 1 && isL2) {
            // layer 2 for step t-1, reading h1_{t-1} (= buffer 'prev')
            const float* hrow = &h1buf[prev][b2i][0];
            float acc = 0.0f;
#pragma unroll
            for (int jb = 0; jb < 25; ++jb) {
                const float4 h4 = *(const float4*)(hrow + 4 * jb);
                acc = fmaf(wreg[4 * jb + 0], h4.x, acc);
                acc = fmaf(wreg[4 * jb + 1], h4.y, acc);
                acc = fmaf(wreg[4 * jb + 2], h4.z, acc);
                acc = fmaf(wreg[4 * jb + 3], h4.w, acc);
            }
            const float pre = acc + wh2 * h2 + bias2;
            const float v = (gg == 2) ? ftanh(pre) : fsig(pre);
            const int base = m & ~3;
            const float vi = __shfl(v, base + 0);
            const float vf = __shfl(v, base + 1);
            const float vg = __shfl(v, base + 2);
            const float vo = __shfl(v, base + 3);
            c2 = vf * c2 + vi * vg;
            h2 = vo * ftanh(c2);
            if (gg == 0) out[(size_t)(bg0 + b2i) * TT + (t - 1)] = h2;
        }

        __syncthreads();
    }
}

extern "C" void kernel_launch(void* const* d_in, const int* in_sizes, int n_in,
                              void* d_out, int out_size, void* d_ws, size_t ws_size,
                              hipStream_t stream) {
    const float* input = (const float*)d_in[0];
    const float* W_ih1 = (const float*)d_in[1];
    const float* W_hh1 = (const float*)d_in[2];
    const float* b_ih1 = (const float*)d_in[3];
    const float* b_hh1 = (const float*)d_in[4];
    const float* W_ih2 = (const float*)d_in[5];
    const float* W_hh2 = (const float*)d_in[6];
    const float* b_ih2 = (const float*)d_in[7];
    const float* b_hh2 = (const float*)d_in[8];
    float* out = (float*)d_out;

    dim3 grid(BB / NB);   // 256 workgroups, 16 chains each
    dim3 block(WG);       // 512 threads = 8 waves
    lstm2_kernel<<<grid, block, 0, stream>>>(input, W_ih1, W_hh1, b_ih1, b_hh1,
                                             W_ih2, W_hh2, b_ih2, b_hh2, out);
}

// Round 4
// 6469.795 us; speedup vs baseline: 3.8348x; 3.8348x over previous
//
#include <hip/hip_runtime.h>
#include <math.h>

// Problem constants (fixed by the harness).
#define BB 4096
#define TT 2048
#define LL 100

constexpr int NB = 16;       // batch items per block (= MFMA M)
constexpr int WG = 512;      // 8 waves
constexpr int XTILE = 64;    // input timesteps staged per LDS tile
constexpr int PSTR = 402;    // preact stride (floats) per item: 4S%32=8 -> <=2-way store conflicts
constexpr int HSTR = 104;    // h1 fp32 stride (16B-aligned rows for b128)
constexpr int WSTR = 104;    // W_ih2 LDS stride

typedef short bf16x8 __attribute__((ext_vector_type(8)));  // 8 bf16 (guide-verified frag type)
typedef float f32x4 __attribute__((ext_vector_type(4)));

union AF { int4 v; bf16x8 f; };

__device__ __forceinline__ unsigned short bf16rn(float x) {  // fp32 -> bf16 round-nearest-even
    unsigned int u = __float_as_uint(x);
    u += 0x7fffu + ((u >> 16) & 1u);
    return (unsigned short)(u >> 16);
}
__device__ __forceinline__ float bf16f(unsigned short h) {
    return __uint_as_float(((unsigned int)h) << 16);
}
__device__ __forceinline__ float fsig(float x) { return 1.0f / (1.0f + __expf(-x)); }
__device__ __forceinline__ float ftanh(float x) {
    float a = fabsf(x);
    float e = __expf(2.0f * a);
    float r = 1.0f - 2.0f / (e + 1.0f);
    return copysignf(r, x);
}

// Per step per block: PreAct[16 items][400 rows] = h1[16][100] @ W_hh1^T via
// mfma_f32_16x16x32_bf16, bf16x3-split (w_hi*h_hi + w_hi*h_lo + w_mid*h_hi).
// A-frag layout (verified, m120): A[m=lane&15][k=(lane>>4)*8+j]
// B-frag layout (mirror):        B[k=(lane>>4)*8+j][n=lane&15]
// C/D layout (verified, m89):    col(n)=lane&15, row(m)=(lane>>4)*4+reg
__global__ void __launch_bounds__(WG)
__attribute__((amdgpu_waves_per_eu(2, 2)))
lstm2_kernel(const float* __restrict__ input,   // [B,T]
             const float* __restrict__ W_ih1,   // [400,1]
             const float* __restrict__ W_hh1,   // [400,100]
             const float* __restrict__ b_ih1,   // [400]
             const float* __restrict__ b_hh1,   // [400]
             const float* __restrict__ W_ih2,   // [4,100]
             const float* __restrict__ W_hh2,   // [4,1]
             const float* __restrict__ b_ih2,   // [4]
             const float* __restrict__ b_hh2,   // [4]
             float* __restrict__ out)           // [B,T]
{
    // h1 as bf16 splits in A-fragment-linear order: [buf][split][kt][lane][j]
    __shared__ __align__(16) unsigned short afrag[2][2][4][64][8];   // 16 KB
    __shared__ __align__(16) float pre_f[NB * PSTR];                 // 25.7 KB
    __shared__ __align__(16) float h1f32[2][NB][HSTR];               // 13.3 KB
    __shared__ __align__(16) float xs[NB][XTILE];                    // 4 KB
    __shared__ __align__(16) float wih2s[4][WSTR];                   // 1.7 KB

    const int tid  = threadIdx.x;
    const int wave = tid >> 6;
    const int lane = tid & 63;
    const int col16 = lane & 15;
    const int quad  = lane >> 4;
    const int bg0 = blockIdx.x * NB;

    // ---------------- init ----------------
    for (int i = tid; i < 2 * 2 * 4 * 64 * 8; i += WG) (&afrag[0][0][0][0][0])[i] = 0;
    for (int i = tid; i < 2 * NB * HSTR; i += WG) (&h1f32[0][0][0])[i] = 0.0f;
    if (tid < 400) wih2s[tid / 100][tid % 100] = W_ih2[tid];

    // N-tile ownership: waves 0-4: 3 tiles, 5-6: 4, 7: 2 (wave 7 also runs layer 2)
    const int cnt = (wave < 5) ? 3 : ((wave < 7) ? 4 : 2);
    const int beg = 3 * wave + ((wave > 5) ? (wave - 5) : 0);

    // Persistent B-fragments (W_hh1 splits) in VGPRs: up to 4 tiles x 4 kt x 2 splits
    bf16x8 bhi[4][4], bmid[4][4];
#pragma unroll
    for (int ti = 0; ti < 4; ++ti) {
#pragma unroll
        for (int kt = 0; kt < 4; ++kt) {
            if (ti < cnt) {
                const int c = 16 * (beg + ti) + col16;   // W row (gate-unit), < 400
#pragma unroll
                for (int j = 0; j < 8; ++j) {
                    const int k = 32 * kt + quad * 8 + j;
                    const float w = (k < LL) ? W_hh1[c * LL + k] : 0.0f;
                    const unsigned short hh = bf16rn(w);
                    bhi[ti][kt][j] = (short)hh;
                    bmid[ti][kt][j] = (short)bf16rn(w - bf16f(hh));
                }
            } else {
#pragma unroll
                for (int j = 0; j < 8; ++j) { bhi[ti][kt][j] = 0; bmid[ti][kt][j] = 0; }
            }
        }
    }

    // Elementwise role (threads 0..399): unit u, item group q (items 4q..4q+3)
    const int u = tid >> 2;
    const int q = tid & 3;
    float wx0 = 0, wx1 = 0, wx2 = 0, wx3 = 0, bs0 = 0, bs1 = 0, bs2 = 0, bs3 = 0;
    float c1a[4] = {0.f, 0.f, 0.f, 0.f};
    if (tid < 400) {
        wx0 = W_ih1[u];            bs0 = b_ih1[u] + b_hh1[u];
        wx1 = W_ih1[100 + u];      bs1 = b_ih1[100 + u] + b_hh1[100 + u];
        wx2 = W_ih1[200 + u];      bs2 = b_ih1[200 + u] + b_hh1[200 + u];
        wx3 = W_ih1[300 + u];      bs3 = b_ih1[300 + u] + b_hh1[300 + u];
    }
    const int kt_u = u >> 5;               // A-frag coords for this unit
    const int lnb  = ((u >> 3) & 3) * 16;
    const int j_u  = u & 7;

    // Layer-2 role (wave 7): lane = 4*item + gate
    const int item = (lane >> 2) & 15;
    const int gg = lane & 3;
    float wh2 = 0.f, bs2l = 0.f, h2 = 0.f, c2 = 0.f;
    if (wave == 7) { wh2 = W_hh2[gg]; bs2l = b_ih2[gg] + b_hh2[gg]; }

    __syncthreads();

    // ---------------- time loop ----------------
    for (int t = 0; t <= TT; ++t) {
        if (t < TT && (t & (XTILE - 1)) == 0) {
            for (int i2 = tid; i2 < NB * XTILE; i2 += WG) {
                const int b = i2 >> 6, ti2 = i2 & (XTILE - 1);
                xs[b][ti2] = input[(size_t)(bg0 + b) * TT + t + ti2];
            }
            __syncthreads();
        }
        const int p = t & 1, pn = p ^ 1;

        // -------- Phase A: MFMA preacts for step t (reads afrag[p] = h1_{t-1}) --------
        if (t < TT) {
            AF ahi[4], alo[4];
#pragma unroll
            for (int kt = 0; kt < 4; ++kt) {
                ahi[kt].v = *(const int4*)&afrag[p][0][kt][lane][0];
                alo[kt].v = *(const int4*)&afrag[p][1][kt][lane][0];
            }
            f32x4 acc[4];
#pragma unroll
            for (int ti = 0; ti < 4; ++ti) acc[ti] = (f32x4){0.f, 0.f, 0.f, 0.f};
            // pass 1: w_hi * h_hi
#pragma unroll
            for (int kt = 0; kt < 4; ++kt)
#pragma unroll
                for (int ti = 0; ti < 4; ++ti)
                    if (ti < cnt)
                        acc[ti] = __builtin_amdgcn_mfma_f32_16x16x32_bf16(ahi[kt].f, bhi[ti][kt], acc[ti], 0, 0, 0);
            // pass 2: w_hi * h_lo
#pragma unroll
            for (int kt = 0; kt < 4; ++kt)
#pragma unroll
                for (int ti = 0; ti < 4; ++ti)
                    if (ti < cnt)
                        acc[ti] = __builtin_amdgcn_mfma_f32_16x16x32_bf16(alo[kt].f, bhi[ti][kt], acc[ti], 0, 0, 0);
            // pass 3: w_mid * h_hi
#pragma unroll
            for (int kt = 0; kt < 4; ++kt)
#pragma unroll
                for (int ti = 0; ti < 4; ++ti)
                    if (ti < cnt)
                        acc[ti] = __builtin_amdgcn_mfma_f32_16x16x32_bf16(ahi[kt].f, bmid[ti][kt], acc[ti], 0, 0, 0);
            // store preacts: D row m = quad*4+r (item), col c = W row
#pragma unroll
            for (int ti = 0; ti < 4; ++ti)
                if (ti < cnt) {
                    const int c = 16 * (beg + ti) + col16;
#pragma unroll
                    for (int r = 0; r < 4; ++r)
                        pre_f[(quad * 4 + r) * PSTR + c] = acc[ti][r];
                }
        }

        // -------- Layer 2 for step t-1 (wave 7; reads h1f32[p] = h1_{t-1}) --------
        if (t >= 1 && wave == 7) {
            const float* hr = &h1f32[p][item][0];
            float acc2 = 0.0f;
#pragma unroll
            for (int jb = 0; jb < 25; ++jb) {
                const float4 h4 = *(const float4*)(hr + 4 * jb);
                const float4 w4 = *(const float4*)(&wih2s[gg][4 * jb]);
                acc2 = fmaf(h4.x, w4.x, acc2);
                acc2 = fmaf(h4.y, w4.y, acc2);
                acc2 = fmaf(h4.z, w4.z, acc2);
                acc2 = fmaf(h4.w, w4.w, acc2);
            }
            const float pre2 = acc2 + wh2 * h2 + bs2l;
            const float v = (gg == 2) ? ftanh(pre2) : fsig(pre2);
            const int vb = __float_as_int(v);
            const float vi = __int_as_float(__builtin_amdgcn_mov_dpp(vb, 0x00, 0xF, 0xF, true));
            const float vf = __int_as_float(__builtin_amdgcn_mov_dpp(vb, 0x55, 0xF, 0xF, true));
            const float vg = __int_as_float(__builtin_amdgcn_mov_dpp(vb, 0xAA, 0xF, 0xF, true));
            const float vo = __int_as_float(__builtin_amdgcn_mov_dpp(vb, 0xFF, 0xF, 0xF, true));
            c2 = vf * c2 + vi * vg;
            h2 = vo * ftanh(c2);
            if (gg == 0) out[(size_t)(bg0 + item) * TT + (t - 1)] = h2;
        }

        __syncthreads();   // preacts visible; afrag[pn]/h1f32[pn] free to overwrite

        // -------- Phase B: cell update -> h1_t (writes afrag[pn], h1f32[pn]) --------
        if (t < TT && tid < 400) {
            const int tmod = t & (XTILE - 1);
#pragma unroll
            for (int i3 = 0; i3 < 4; ++i3) {
                const int m = 4 * q + i3;
                const float xv = xs[m][tmod];
                const float* pr = &pre_f[m * PSTR];
                const float gi = pr[u]       + wx0 * xv + bs0;
                const float gf = pr[100 + u] + wx1 * xv + bs1;
                const float gG = pr[200 + u] + wx2 * xv + bs2;
                const float go = pr[300 + u] + wx3 * xv + bs3;
                const float iv = fsig(gi);
                const float fv = fsig(gf);
                const float gv = ftanh(gG);
                const float ov = fsig(go);
                const float c = fv * c1a[i3] + iv * gv;
                c1a[i3] = c;
                const float h = ov * ftanh(c);
                h1f32[pn][m][u] = h;
                const unsigned short hh = bf16rn(h);
                const unsigned short hl = bf16rn(h - bf16f(hh));
                afrag[pn][0][kt_u][lnb + m][j_u] = hh;
                afrag[pn][1][kt_u][lnb + m][j_u] = hl;
            }
        }

        __syncthreads();   // h1_t visible for step t+1's Phase A
    }
}

extern "C" void kernel_launch(void* const* d_in, const int* in_sizes, int n_in,
                              void* d_out, int out_size, void* d_ws, size_t ws_size,
                              hipStream_t stream) {
    const float* input = (const float*)d_in[0];
    const float* W_ih1 = (const float*)d_in[1];
    const float* W_hh1 = (const float*)d_in[2];
    const float* b_ih1 = (const float*)d_in[3];
    const float* b_hh1 = (const float*)d_in[4];
    const float* W_ih2 = (const float*)d_in[5];
    const float* W_hh2 = (const float*)d_in[6];
    const float* b_ih2 = (const float*)d_in[7];
    const float* b_hh2 = (const float*)d_in[8];
    float* out = (float*)d_out;

    dim3 grid(BB / NB);   // 256 workgroups, 16 chains each -> 1 per CU
    dim3 block(WG);       // 512 threads = 8 waves
    lstm2_kernel<<<grid, block, 0, stream>>>(input, W_ih1, W_hh1, b_ih1, b_hh1,
                                             W_ih2, W_hh2, b_ih2, b_hh2, out);
}

// Round 5
// 3606.763 us; speedup vs baseline: 6.8788x; 1.7938x over previous
//
#include <hip/hip_runtime.h>
#include <math.h>

// Problem constants (fixed by the harness).
#define BB 4096
#define TT 2048
#define LL 100

constexpr int NB = 16;       // batch items per block (= MFMA M)
constexpr int WG = 512;      // 8 waves: 0-6 = layer-1 (28 padded N-tiles), 7 = layer-2
constexpr int XTILE = 64;    // input timesteps staged per LDS tile
constexpr int XSTR = 20;     // xs_t row stride (dwords): 16B-aligned b128 reads, spread banks
constexpr int HSTR = 104;    // h1 fp32 stride (16B-aligned rows)
constexpr int WSTR = 104;    // W_ih2 LDS stride

typedef short bf16x8 __attribute__((ext_vector_type(8)));
typedef float f32x4 __attribute__((ext_vector_type(4)));

union AF { int4 v; bf16x8 f; unsigned int w[4]; };

__device__ __forceinline__ unsigned int bf16rn(float x) {  // fp32 -> bf16 RNE (low 16 of result)
    unsigned int u = __float_as_uint(x);
    u += 0x7fffu + ((u >> 16) & 1u);
    return u >> 16;
}
__device__ __forceinline__ float bf16f(unsigned int h) {
    return __uint_as_float(h << 16);
}
// v_rcp_f32 (~1ulp) instead of IEEE division: without fast-math, 1.0f/x emits
// v_div_scale+v_div_fmas+v_div_fixup (~12 instr) -- that was R4's hidden VALU bloat.
__device__ __forceinline__ float frcp(float x) { return __builtin_amdgcn_rcpf(x); }
__device__ __forceinline__ float fsig(float x) { return frcp(1.0f + __expf(-x)); }
__device__ __forceinline__ float ftanh(float x) {
    float a = fabsf(x);
    float r = 1.0f - 2.0f * frcp(1.0f + __expf(2.0f * a));  // exp=inf -> rcp=0 -> r=1
    return copysignf(r, x);
}

// Layer-1 tiling: each gate padded 100->112 rows; 28 N-tiles of 16. Wave w (0..6)
// owns tiles {7g+w, g=0..3} = all 4 gates of units 16w..16w+15. MFMA D-frag lane
// (col16=unit-offset, quad*4+r=item) therefore holds all 4 gate preacts of
// (item, unit) locally -> cell update is in-register, no pre-act LDS round-trip,
// ONE barrier per step.
// Frag layouts (R4-verified on HW): A[m=lane&15][k=32kt+8quad+j];
// B[k=32kt+8quad+j][n=lane&15]; D col=lane&15, row=quad*4+reg.
__global__ void __launch_bounds__(WG)
__attribute__((amdgpu_waves_per_eu(2, 2)))
lstm2_kernel(const float* __restrict__ input,   // [B,T]
             const float* __restrict__ W_ih1,   // [400,1]
             const float* __restrict__ W_hh1,   // [400,100]
             const float* __restrict__ b_ih1,   // [400]
             const float* __restrict__ b_hh1,   // [400]
             const float* __restrict__ W_ih2,   // [4,100]
             const float* __restrict__ W_hh2,   // [4,1]
             const float* __restrict__ b_ih2,   // [4]
             const float* __restrict__ b_hh2,   // [4]
             float* __restrict__ out)           // [B,T]
{
    // h1 as packed bf16 splits (hi | lo<<16) in A-frag-linear order: [buf][kt][lane][j]
    __shared__ __align__(16) unsigned int afragP[2][4][64][8];   // 16 KB
    __shared__ __align__(16) float h1f32[2][NB][HSTR];           // 13.3 KB
    __shared__ __align__(16) float xs_t[XTILE][XSTR];            // 5.1 KB (transposed input)
    __shared__ __align__(16) float wih2s[4][WSTR];               // 1.7 KB

    const int tid = threadIdx.x;
    const int wave = tid >> 6;
    const int lane = tid & 63;
    const int col16 = lane & 15;
    const int quad = lane >> 4;
    const int bg0 = blockIdx.x * NB;

    // ---------------- init ----------------
    for (int i = tid; i < 2 * 4 * 64 * 8; i += WG) (&afragP[0][0][0][0])[i] = 0u;
    for (int i = tid; i < 2 * NB * HSTR; i += WG) (&h1f32[0][0][0])[i] = 0.0f;
    if (tid < 400) wih2s[tid / 100][tid % 100] = W_ih2[tid];

    const int uu = 16 * wave + col16;            // unit owned by this lane (waves 0-6)
    const bool uvalid = (wave < 7) && (uu < LL); // pad lanes (wave 6, uu>=100) produce zeros

    // Persistent B-fragments: W_hh1 bf16 hi/mid splits, 4 gates x 4 kt
    bf16x8 bhi[4][4], bmid[4][4];
#pragma unroll
    for (int g = 0; g < 4; ++g)
#pragma unroll
        for (int kt = 0; kt < 4; ++kt)
#pragma unroll
            for (int j = 0; j < 8; ++j) {
                const int k = 32 * kt + 8 * quad + j;
                float w = 0.0f;
                if (wave < 7 && uvalid && k < LL) w = W_hh1[(100 * g + uu) * LL + k];
                const unsigned int hh = bf16rn(w);
                bhi[g][kt][j] = (short)hh;
                bmid[g][kt][j] = (short)bf16rn(w - bf16f(hh));
            }

    float wx[4], bs[4];
    float c1[4] = {0.f, 0.f, 0.f, 0.f};
#pragma unroll
    for (int g = 0; g < 4; ++g) {
        wx[g] = uvalid ? W_ih1[100 * g + uu] : 0.0f;
        bs[g] = uvalid ? (b_ih1[100 * g + uu] + b_hh1[100 * g + uu]) : 0.0f;
    }
    const int kt_u = uu >> 5;                 // A-frag write coords for this unit
    const int lnb = ((uu >> 3) & 3) * 16;
    const int j_u = uu & 7;

    // Layer-2 role (wave 7): lane = 4*item + gate
    const int item = (lane >> 2) & 15;
    const int gg = lane & 3;
    float wh2 = 0.f, bs2 = 0.f, h2 = 0.f, c2 = 0.f;
    if (wave == 7) { wh2 = W_hh2[gg]; bs2 = b_ih2[gg] + b_hh2[gg]; }

    __syncthreads();

    // ---------------- time loop (one barrier per step) ----------------
    for (int t = 0; t <= TT; ++t) {
        const int p = t & 1, pn = p ^ 1;

        if (t < TT && (t & (XTILE - 1)) == 0) {
            // stage transposed input tile: coalesced read, strided LDS write
            const int m = tid >> 5, t0 = tid & 31;
            const float v0 = input[(size_t)(bg0 + m) * TT + t + t0];
            const float v1 = input[(size_t)(bg0 + m) * TT + t + t0 + 32];
            xs_t[t0][m] = v0;
            xs_t[t0 + 32][m] = v1;
            __syncthreads();
        }

        if (t < TT && wave < 7) {
            // ---- load + unpack A-fragments (h1_{t-1}) ----
            AF ahi[4], alo[4];
#pragma unroll
            for (int kt = 0; kt < 4; ++kt) {
                const int4 r0 = *(const int4*)&afragP[p][kt][lane][0];
                const int4 r1 = *(const int4*)&afragP[p][kt][lane][4];
                const unsigned int ww[8] = {(unsigned)r0.x, (unsigned)r0.y, (unsigned)r0.z, (unsigned)r0.w,
                                            (unsigned)r1.x, (unsigned)r1.y, (unsigned)r1.z, (unsigned)r1.w};
#pragma unroll
                for (int d = 0; d < 4; ++d) {
                    ahi[kt].w[d] = (ww[2 * d] & 0xffffu) | (ww[2 * d + 1] << 16);
                    alo[kt].w[d] = (ww[2 * d] >> 16) | (ww[2 * d + 1] & 0xffff0000u);
                }
            }
            // ---- MFMA: 3-pass bf16 split, 4 gates x 4 kt ----
            f32x4 acc[4];
#pragma unroll
            for (int g = 0; g < 4; ++g) acc[g] = (f32x4){0.f, 0.f, 0.f, 0.f};
#pragma unroll
            for (int kt = 0; kt < 4; ++kt)
#pragma unroll
                for (int g = 0; g < 4; ++g)
                    acc[g] = __builtin_amdgcn_mfma_f32_16x16x32_bf16(ahi[kt].f, bhi[g][kt], acc[g], 0, 0, 0);
#pragma unroll
            for (int kt = 0; kt < 4; ++kt)
#pragma unroll
                for (int g = 0; g < 4; ++g)
                    acc[g] = __builtin_amdgcn_mfma_f32_16x16x32_bf16(alo[kt].f, bhi[g][kt], acc[g], 0, 0, 0);
#pragma unroll
            for (int kt = 0; kt < 4; ++kt)
#pragma unroll
                for (int g = 0; g < 4; ++g)
                    acc[g] = __builtin_amdgcn_mfma_f32_16x16x32_bf16(ahi[kt].f, bmid[g][kt], acc[g], 0, 0, 0);

            // ---- in-register cell update for (items 4q..4q+3, unit uu) ----
            const int tmod = t & (XTILE - 1);
            const float4 x4 = *(const float4*)&xs_t[tmod][4 * quad];
            const float xr[4] = {x4.x, x4.y, x4.z, x4.w};
#pragma unroll
            for (int r = 0; r < 4; ++r) {
                const int m = 4 * quad + r;
                const float gi = acc[0][r] + fmaf(wx[0], xr[r], bs[0]);
                const float gf = acc[1][r] + fmaf(wx[1], xr[r], bs[1]);
                const float gG = acc[2][r] + fmaf(wx[2], xr[r], bs[2]);
                const float go = acc[3][r] + fmaf(wx[3], xr[r], bs[3]);
                const float iv = fsig(gi);
                const float fv = fsig(gf);
                const float gv = ftanh(gG);
                const float ov = fsig(go);
                const float c = fv * c1[r] + iv * gv;
                c1[r] = c;
                const float h = uvalid ? (ov * ftanh(c)) : 0.0f;  // pad units must stay 0
                const unsigned int hh = bf16rn(h);
                const unsigned int hl = bf16rn(h - bf16f(hh));
                afragP[pn][kt_u][lnb + m][j_u] = hh | (hl << 16);
                if (uvalid) h1f32[pn][m][uu] = h;                 // uu<100 only (row stride 104)
            }
        }

        // ---- layer 2 for step t-1 (wave 7; reads h1f32[p] = h1_{t-1}) ----
        if (t >= 1 && wave == 7) {
            const float* hr = &h1f32[p][item][0];
            float a2 = 0.0f;
#pragma unroll
            for (int jb = 0; jb < 25; ++jb) {
                const float4 h4 = *(const float4*)(hr + 4 * jb);
                const float4 w4 = *(const float4*)&wih2s[gg][4 * jb];
                a2 = fmaf(h4.x, w4.x, a2);
                a2 = fmaf(h4.y, w4.y, a2);
                a2 = fmaf(h4.z, w4.z, a2);
                a2 = fmaf(h4.w, w4.w, a2);
            }
            const float pre2 = a2 + wh2 * h2 + bs2;
            const float v = (gg == 2) ? ftanh(pre2) : fsig(pre2);
            const int vb = __float_as_int(v);
            const float vi = __int_as_float(__builtin_amdgcn_mov_dpp(vb, 0x00, 0xF, 0xF, true));
            const float vf = __int_as_float(__builtin_amdgcn_mov_dpp(vb, 0x55, 0xF, 0xF, true));
            const float vg = __int_as_float(__builtin_amdgcn_mov_dpp(vb, 0xAA, 0xF, 0xF, true));
            const float vo = __int_as_float(__builtin_amdgcn_mov_dpp(vb, 0xFF, 0xF, 0xF, true));
            c2 = vf * c2 + vi * vg;
            h2 = vo * ftanh(c2);
            if (gg == 0) out[(size_t)(bg0 + item) * TT + (t - 1)] = h2;
        }

        __syncthreads();   // h1_t (afragP[pn], h1f32[pn]) visible for step t+1
    }
}

extern "C" void kernel_launch(void* const* d_in, const int* in_sizes, int n_in,
                              void* d_out, int out_size, void* d_ws, size_t ws_size,
                              hipStream_t stream) {
    const float* input = (const float*)d_in[0];
    const float* W_ih1 = (const float*)d_in[1];
    const float* W_hh1 = (const float*)d_in[2];
    const float* b_ih1 = (const float*)d_in[3];
    const float* b_hh1 = (const float*)d_in[4];
    const float* W_ih2 = (const float*)d_in[5];
    const float* W_hh2 = (const float*)d_in[6];
    const float* b_ih2 = (const float*)d_in[7];
    const float* b_hh2 = (const float*)d_in[8];
    float* out = (float*)d_out;

    dim3 grid(BB / NB);   // 256 workgroups, 16 chains each -> 1 per CU
    dim3 block(WG);       // 512 threads = 8 waves
    lstm2_kernel<<<grid, block, 0, stream>>>(input, W_ih1, W_hh1, b_ih1, b_hh1,
                                             W_ih2, W_hh2, b_ih2, b_hh2, out);
}

// Round 6
// 3464.940 us; speedup vs baseline: 7.1603x; 1.0409x over previous
//
#include <hip/hip_runtime.h>
#include <math.h>

// Problem constants (fixed by the harness).
#define BB 4096
#define TT 2048
#define LL 100

constexpr int NB = 16;       // batch items per block (= MFMA M)
constexpr int WG = 512;      // 8 waves: 0-6 layer-1 (28 padded N-tiles), 7 layer-2
constexpr int XTILE = 64;    // input timesteps staged per LDS tile
constexpr int XSTR = 20;     // xs_t row stride (dwords)
constexpr int HSTR = 108;    // h1 fp32 stride: 108%32=12 -> wave-7 b128 reads conflict-free
constexpr int WSTR = 104;    // W_ih2 LDS stride

// afrag addressing: dword offset = kt*576 + row*8 + (row>>2)*4 + j.
// The +16B pad every 4 rows makes lane-parallel b128 reads hit all 32 banks
// exactly once per 8 lanes (conflict-free) and spreads the j_u scatter-writes
// to <=3-way (R5's stride-8 layout was 8-way on writes = 2.36e8 conflicts).
#define AOFF(kt, row) ((kt) * 576 + (row) * 8 + (((row) >> 2) << 2))

typedef short bf16x8 __attribute__((ext_vector_type(8)));
typedef float f32x4 __attribute__((ext_vector_type(4)));

union AF { int4 v; bf16x8 f; unsigned int w[4]; };

__device__ __forceinline__ unsigned int bf16rn(float x) {  // fp32 -> bf16 RNE
    unsigned int u = __float_as_uint(x);
    u += 0x7fffu + ((u >> 16) & 1u);
    return u >> 16;
}
__device__ __forceinline__ float bf16f(unsigned int h) { return __uint_as_float(h << 16); }
__device__ __forceinline__ float frcp(float x) { return __builtin_amdgcn_rcpf(x); }
__device__ __forceinline__ float fsig(float x) { return frcp(1.0f + __expf(-x)); }
// Branch-free tanh: mathematically exact identity; exp(+-inf) saturates cleanly.
// Drops abs/copysign vs R5 (~25 VALU/wave/step).
__device__ __forceinline__ float ftanh(float x) {
    return 1.0f - 2.0f * frcp(1.0f + __expf(2.0f * x));
}

__device__ __forceinline__ unsigned int perm_lo(unsigned int w0, unsigned int w1) {
#if __has_builtin(__builtin_amdgcn_perm)
    return __builtin_amdgcn_perm(w1, w0, 0x05040100u);  // (w0&0xffff)|(w1<<16)
#else
    return (w0 & 0xffffu) | (w1 << 16);
#endif
}
__device__ __forceinline__ unsigned int perm_hi(unsigned int w0, unsigned int w1) {
#if __has_builtin(__builtin_amdgcn_perm)
    return __builtin_amdgcn_perm(w1, w0, 0x07060302u);  // (w0>>16)|(w1&0xffff0000)
#else
    return (w0 >> 16) | (w1 & 0xffff0000u);
#endif
}

// Layer-1: gates padded 100->112 rows, 28 N-tiles; wave w (0..6) owns all 4
// gates of units 16w..16w+15 -> cell update fully in-register, 1 barrier/step.
// Frag layouts (HW-verified R4/R5): A[m=lane&15][k=32kt+8quad+j];
// B[k][n=lane&15]; D col=lane&15, row=quad*4+reg.
__global__ void __launch_bounds__(WG)
__attribute__((amdgpu_waves_per_eu(2, 2)))
lstm2_kernel(const float* __restrict__ input,   // [B,T]
             const float* __restrict__ W_ih1,   // [400,1]
             const float* __restrict__ W_hh1,   // [400,100]
             const float* __restrict__ b_ih1,   // [400]
             const float* __restrict__ b_hh1,   // [400]
             const float* __restrict__ W_ih2,   // [4,100]
             const float* __restrict__ W_hh2,   // [4,1]
             const float* __restrict__ b_ih2,   // [4]
             const float* __restrict__ b_hh2,   // [4]
             float* __restrict__ out)           // [B,T]
{
    __shared__ __align__(16) unsigned int afragP[2][2304];   // 18.4 KB (padded layout)
    __shared__ __align__(16) float h1f32[2][NB][HSTR];       // 13.8 KB
    __shared__ __align__(16) float xs_t[XTILE][XSTR];        // 5.1 KB (transposed input)
    __shared__ __align__(16) float wih2s[4][WSTR];           // 1.7 KB

    const int tid = threadIdx.x;
    const int wave = tid >> 6;
    const int lane = tid & 63;
    const int col16 = lane & 15;
    const int quad = lane >> 4;
    const int bg0 = blockIdx.x * NB;

    // ---------------- init ----------------
    for (int i = tid; i < 2 * 2304; i += WG) (&afragP[0][0])[i] = 0u;
    for (int i = tid; i < 2 * NB * HSTR; i += WG) (&h1f32[0][0][0])[i] = 0.0f;
    if (tid < 400) wih2s[tid / 100][tid % 100] = W_ih2[tid];

    const int uu = 16 * wave + col16;            // unit owned by this lane (waves 0-6)
    const bool uvalid = (wave < 7) && (uu < LL); // pad lanes produce zeros

    // Persistent B-fragments: W_hh1 bf16 hi/mid splits, 4 gates x 4 kt
    bf16x8 bhi[4][4], bmid[4][4];
#pragma unroll
    for (int g = 0; g < 4; ++g)
#pragma unroll
        for (int kt = 0; kt < 4; ++kt)
#pragma unroll
            for (int j = 0; j < 8; ++j) {
                const int k = 32 * kt + 8 * quad + j;
                float w = 0.0f;
                if (wave < 7 && uvalid && k < LL) w = W_hh1[(100 * g + uu) * LL + k];
                const unsigned int hh = bf16rn(w);
                bhi[g][kt][j] = (short)hh;
                bmid[g][kt][j] = (short)bf16rn(w - bf16f(hh));
            }

    float wx[4], bs[4];
    float c1[4] = {0.f, 0.f, 0.f, 0.f};
#pragma unroll
    for (int g = 0; g < 4; ++g) {
        wx[g] = uvalid ? W_ih1[100 * g + uu] : 0.0f;
        bs[g] = uvalid ? (b_ih1[100 * g + uu] + b_hh1[100 * g + uu]) : 0.0f;
    }
    const int kt_u = uu >> 5;
    const int lnb = ((uu >> 3) & 3) * 16;
    const int j_u = uu & 7;

    // Layer-2 role (wave 7): lane = 4*item + gate
    const int item = (lane >> 2) & 15;
    const int gg = lane & 3;
    float wh2 = 0.f, bs2 = 0.f, h2 = 0.f, c2 = 0.f;
    if (wave == 7) { wh2 = W_hh2[gg]; bs2 = b_ih2[gg] + b_hh2[gg]; }

    __syncthreads();

    // ---------------- time loop (one barrier per step) ----------------
    for (int t = 0; t <= TT; ++t) {
        const int p = t & 1, pn = p ^ 1;

        if (t < TT && (t & (XTILE - 1)) == 0) {
            const int m = tid >> 5, t0 = tid & 31;
            const float v0 = input[(size_t)(bg0 + m) * TT + t + t0];
            const float v1 = input[(size_t)(bg0 + m) * TT + t + t0 + 32];
            xs_t[t0][m] = v0;
            xs_t[t0 + 32][m] = v1;
            __syncthreads();
        }

        if (t < TT && wave < 7) {
            // ---- load + v_perm unpack A-fragments (h1_{t-1}) ----
            AF ahi[4], alo[4];
#pragma unroll
            for (int kt = 0; kt < 4; ++kt) {
                const unsigned int* ap = &afragP[p][AOFF(kt, lane)];
                const int4 r0 = *(const int4*)ap;
                const int4 r1 = *(const int4*)(ap + 4);
                const unsigned int ww[8] = {(unsigned)r0.x, (unsigned)r0.y, (unsigned)r0.z, (unsigned)r0.w,
                                            (unsigned)r1.x, (unsigned)r1.y, (unsigned)r1.z, (unsigned)r1.w};
#pragma unroll
                for (int d = 0; d < 4; ++d) {
                    ahi[kt].w[d] = perm_lo(ww[2 * d], ww[2 * d + 1]);
                    alo[kt].w[d] = perm_hi(ww[2 * d], ww[2 * d + 1]);
                }
            }

            const int tmod = t & (XTILE - 1);
            const float4 x4 = *(const float4*)&xs_t[tmod][4 * quad];
            const float xr[4] = {x4.x, x4.y, x4.z, x4.w};
            float act[4][4];  // [gate][r]

            // ---- gate pair (i,f): 24 MFMA (2 indep chains), then activate early ----
            {
                f32x4 a0 = (f32x4){0.f, 0.f, 0.f, 0.f}, a1 = a0;
#pragma unroll
                for (int kt = 0; kt < 4; ++kt) {
                    a0 = __builtin_amdgcn_mfma_f32_16x16x32_bf16(ahi[kt].f, bhi[0][kt], a0, 0, 0, 0);
                    a1 = __builtin_amdgcn_mfma_f32_16x16x32_bf16(ahi[kt].f, bhi[1][kt], a1, 0, 0, 0);
                }
#pragma unroll
                for (int kt = 0; kt < 4; ++kt) {
                    a0 = __builtin_amdgcn_mfma_f32_16x16x32_bf16(alo[kt].f, bhi[0][kt], a0, 0, 0, 0);
                    a1 = __builtin_amdgcn_mfma_f32_16x16x32_bf16(alo[kt].f, bhi[1][kt], a1, 0, 0, 0);
                }
#pragma unroll
                for (int kt = 0; kt < 4; ++kt) {
                    a0 = __builtin_amdgcn_mfma_f32_16x16x32_bf16(ahi[kt].f, bmid[0][kt], a0, 0, 0, 0);
                    a1 = __builtin_amdgcn_mfma_f32_16x16x32_bf16(ahi[kt].f, bmid[1][kt], a1, 0, 0, 0);
                }
#pragma unroll
                for (int r = 0; r < 4; ++r) {
                    act[0][r] = fsig(a0[r] + fmaf(wx[0], xr[r], bs[0]));
                    act[1][r] = fsig(a1[r] + fmaf(wx[1], xr[r], bs[1]));
                }
            }
            // ---- gate pair (g,o): overlaps with pair (i,f)'s transcendentals ----
            {
                f32x4 a2 = (f32x4){0.f, 0.f, 0.f, 0.f}, a3 = a2;
#pragma unroll
                for (int kt = 0; kt < 4; ++kt) {
                    a2 = __builtin_amdgcn_mfma_f32_16x16x32_bf16(ahi[kt].f, bhi[2][kt], a2, 0, 0, 0);
                    a3 = __builtin_amdgcn_mfma_f32_16x16x32_bf16(ahi[kt].f, bhi[3][kt], a3, 0, 0, 0);
                }
#pragma unroll
                for (int kt = 0; kt < 4; ++kt) {
                    a2 = __builtin_amdgcn_mfma_f32_16x16x32_bf16(alo[kt].f, bhi[2][kt], a2, 0, 0, 0);
                    a3 = __builtin_amdgcn_mfma_f32_16x16x32_bf16(alo[kt].f, bhi[3][kt], a3, 0, 0, 0);
                }
#pragma unroll
                for (int kt = 0; kt < 4; ++kt) {
                    a2 = __builtin_amdgcn_mfma_f32_16x16x32_bf16(ahi[kt].f, bmid[2][kt], a2, 0, 0, 0);
                    a3 = __builtin_amdgcn_mfma_f32_16x16x32_bf16(ahi[kt].f, bmid[3][kt], a3, 0, 0, 0);
                }
#pragma unroll
                for (int r = 0; r < 4; ++r) {
                    act[2][r] = ftanh(a2[r] + fmaf(wx[2], xr[r], bs[2]));
                    act[3][r] = fsig(a3[r] + fmaf(wx[3], xr[r], bs[3]));
                }
            }

            // ---- cell state + h write-back (packed hi|lo bf16) ----
#pragma unroll
            for (int r = 0; r < 4; ++r) {
                const int m = 4 * quad + r;
                const float c = act[1][r] * c1[r] + act[0][r] * act[2][r];
                c1[r] = c;
                const float h = uvalid ? (act[3][r] * ftanh(c)) : 0.0f;
                const unsigned int hh = bf16rn(h);
                const unsigned int hl = bf16rn(h - bf16f(hh));
                afragP[pn][AOFF(kt_u, lnb + m) + j_u] = hh | (hl << 16);
                if (uvalid) h1f32[pn][m][uu] = h;
            }
        }

        // ---- layer 2 for step t-1 (wave 7; reads h1f32[p] = h1_{t-1}) ----
        if (t >= 1 && wave == 7) {
            const float* hr = &h1f32[p][item][0];
            float a2 = 0.0f;
#pragma unroll
            for (int jb = 0; jb < 25; ++jb) {
                const float4 h4 = *(const float4*)(hr + 4 * jb);
                const float4 w4 = *(const float4*)&wih2s[gg][4 * jb];
                a2 = fmaf(h4.x, w4.x, a2);
                a2 = fmaf(h4.y, w4.y, a2);
                a2 = fmaf(h4.z, w4.z, a2);
                a2 = fmaf(h4.w, w4.w, a2);
            }
            const float pre2 = a2 + wh2 * h2 + bs2;
            const float v = (gg == 2) ? ftanh(pre2) : fsig(pre2);
            const int vb = __float_as_int(v);
            const float vi = __int_as_float(__builtin_amdgcn_mov_dpp(vb, 0x00, 0xF, 0xF, true));
            const float vf = __int_as_float(__builtin_amdgcn_mov_dpp(vb, 0x55, 0xF, 0xF, true));
            const float vg = __int_as_float(__builtin_amdgcn_mov_dpp(vb, 0xAA, 0xF, 0xF, true));
            const float vo = __int_as_float(__builtin_amdgcn_mov_dpp(vb, 0xFF, 0xF, 0xF, true));
            c2 = vf * c2 + vi * vg;
            h2 = vo * ftanh(c2);
            if (gg == 0) out[(size_t)(bg0 + item) * TT + (t - 1)] = h2;
        }

        __syncthreads();   // h1_t (afragP[pn], h1f32[pn]) visible for step t+1
    }
}

extern "C" void kernel_launch(void* const* d_in, const int* in_sizes, int n_in,
                              void* d_out, int out_size, void* d_ws, size_t ws_size,
                              hipStream_t stream) {
    const float* input = (const float*)d_in[0];
    const float* W_ih1 = (const float*)d_in[1];
    const float* W_hh1 = (const float*)d_in[2];
    const float* b_ih1 = (const float*)d_in[3];
    const float* b_hh1 = (const float*)d_in[4];
    const float* W_ih2 = (const float*)d_in[5];
    const float* W_hh2 = (const float*)d_in[6];
    const float* b_ih2 = (const float*)d_in[7];
    const float* b_hh2 = (const float*)d_in[8];
    float* out = (float*)d_out;

    dim3 grid(BB / NB);   // 256 workgroups -> 1 per CU
    dim3 block(WG);       // 512 threads = 8 waves
    lstm2_kernel<<<grid, block, 0, stream>>>(input, W_ih1, W_hh1, b_ih1, b_hh1,
                                             W_ih2, W_hh2, b_ih2, b_hh2, out);
}